// Round 5
// baseline (1080.964 us; speedup 1.0000x reference)
//
#include <hip/hip_runtime.h>
#include <hip/hip_bf16.h>

typedef __attribute__((ext_vector_type(4))) float  f32x4;
typedef __attribute__((ext_vector_type(4))) short  s16x4;
typedef __attribute__((ext_vector_type(8))) short  s16x8;

#define DEVI static __device__ __forceinline__

constexpr int   BQ    = 4096;   // windows
constexpr int   NTOK  = 49;     // tokens per window
constexpr int   DIMC  = 384;
constexpr int   NH    = 12;
constexpr int   HDIM  = 32;
constexpr int   NW    = 64;
constexpr float SCALE_ = 0.17677669529663687f; // 32^-0.5

DEVI ushort f2bf(float f) {
  union { float f; unsigned u; } v; v.f = f;
  unsigned r = v.u + 0x7fffu + ((v.u >> 16) & 1u);
  return (ushort)(r >> 16);
}

// async global->LDS, 16B per lane; LDS dest = wave-uniform base + lane*16
DEVI void async_ld16(const ushort* g, const ushort* l) {
  auto gp = reinterpret_cast<const __attribute__((address_space(1))) unsigned int*>(
      reinterpret_cast<uintptr_t>(g));
  auto lp = reinterpret_cast<__attribute__((address_space(3))) unsigned int*>(
      reinterpret_cast<uintptr_t>(l));
  __builtin_amdgcn_global_load_lds(gp, lp, 16, 0, 0);
}

// ---------------- prep kernels ----------------
__global__ void cast_x_kernel(const float* __restrict__ x, ushort* __restrict__ o, int n8) {
  int i = blockIdx.x * 256 + threadIdx.x;
  const int stride = gridDim.x * 256;
  for (; i < n8; i += stride) {
    f32x4 a = *(const f32x4*)(x + (size_t)i * 8);
    f32x4 b = *(const f32x4*)(x + (size_t)i * 8 + 4);
    s16x8 v;
    v[0] = (short)f2bf(a[0]); v[1] = (short)f2bf(a[1]);
    v[2] = (short)f2bf(a[2]); v[3] = (short)f2bf(a[3]);
    v[4] = (short)f2bf(b[0]); v[5] = (short)f2bf(b[1]);
    v[6] = (short)f2bf(b[2]); v[7] = (short)f2bf(b[3]);
    *(s16x8*)(o + (size_t)i * 8) = v;
  }
}

// one kernel: cast qkv_w, cast proj_w, build combined bias+mask table
constexpr int PREP_N1 = 3 * DIMC * DIMC;           // 442368
constexpr int PREP_N2 = DIMC * DIMC;               // 147456
constexpr int PREP_N3 = NW * NH * NTOK * NTOK;     // 1843968
__global__ void prep_kernel(const float* __restrict__ qkv_w, const float* __restrict__ proj_w,
                            const float* __restrict__ tab, const int* __restrict__ idx,
                            const float* __restrict__ mask,
                            ushort* __restrict__ qw, ushort* __restrict__ pw,
                            float* __restrict__ comb) {
  int i = blockIdx.x * 256 + threadIdx.x;
  if (i < PREP_N1) {
    qw[i] = f2bf(qkv_w[i]);
  } else if (i < PREP_N1 + PREP_N2) {
    int j = i - PREP_N1;
    pw[j] = f2bf(proj_w[j]);
  } else if (i < PREP_N1 + PREP_N2 + PREP_N3) {
    int j = i - PREP_N1 - PREP_N2;
    int rc = j % (NTOK * NTOK);
    int wh = j / (NTOK * NTOK);
    int h = wh % NH, w = wh / NH;
    comb[j] = tab[idx[rc] * NH + h] + mask[(size_t)w * NTOK * NTOK + rc];
  }
}

// ---------------- GEMM: C = A * B^T (+bias), bf16 MFMA ----------------
// A staged via global_load_lds (T2 source-swizzle, 2x16KB double buffer);
// B (small, L2-resident weights) read DIRECT from global to registers —
// not barrier-gated, so B latency pipelines under MFMA freely.
// EPI 0: fp32 C + bias -> outF[m*384+n]
// EPI 1: QKV scatter: Q scaled by SCALE_, bf16 -> Qb[b][h][49][32], Kb same,
//        Vb[b][h][32][64] (transposed, col-padded to 64)
template<int EPI, int K, int NB>
__global__ __launch_bounds__(256) void gemm_bt_kernel(
    const ushort* __restrict__ Ap, const ushort* __restrict__ Bp,
    const float* __restrict__ bias, float* __restrict__ outF,
    ushort* __restrict__ Qb, ushort* __restrict__ Kb, ushort* __restrict__ Vb)
{
  __shared__ ushort As[2][128 * 64];   // 32 KB total
  const int tid  = threadIdx.x;
  const int lane = tid & 63;
  const int wv   = tid >> 6;
  const int wm   = (wv >> 1) * 64, wn = (wv & 1) * 64;
  const int l15  = lane & 15, lg = lane >> 4;

  // bijective XCD-chunked swizzle (gridDim.x divisible by 8)
  const int chunk = gridDim.x >> 3;
  const int wgid  = (blockIdx.x & 7) * chunk + (blockIdx.x >> 3);
  const int nbase = (wgid % NB) * 128;
  const int mbase = (wgid / NB) * 128;

  const int srow  = lane >> 3;                 // row within 8-row segment
  const int scolb = ((lane & 7) ^ srow) * 8;   // PRE-SWIZZLED source chunk (T2)

  const ushort* Abase = Ap + (size_t)(mbase + wv * 32 + srow) * K + scolb;
  const ushort* Bbase = Bp + (size_t)(nbase + wn + l15) * K + lg * 8;

  f32x4 acc[4][4];
  #pragma unroll
  for (int i = 0; i < 4; i++)
    #pragma unroll
    for (int j = 0; j < 4; j++) acc[i][j] = (f32x4){0.f, 0.f, 0.f, 0.f};

  auto stageA = [&](int buf, int k0) {
    #pragma unroll
    for (int i = 0; i < 4; i++) {
      int seg = wv * 4 + i;     // 16 segments of 8 rows x 64 cols
      async_ld16(Abase + (size_t)i * 8 * K + k0, &As[buf][seg * 512]);
    }
  };
  auto compute = [&](int buf, int k0) {
    #pragma unroll
    for (int kk = 0; kk < 2; kk++) {
      s16x8 bfv[4];
      #pragma unroll
      for (int t = 0; t < 4; t++)
        bfv[t] = *(const s16x8*)(Bbase + (size_t)t * 16 * K + k0 + kk * 32);
      s16x8 af[4];
      #pragma unroll
      for (int t = 0; t < 4; t++) {
        int arow = wm + t*16 + l15;
        af[t] = *(const s16x8*)&As[buf][arow * 64 + (((kk*4 + lg) ^ (arow & 7)) << 3)];
      }
      #pragma unroll
      for (int mt = 0; mt < 4; mt++)
        #pragma unroll
        for (int nt = 0; nt < 4; nt++)
          acc[mt][nt] = __builtin_amdgcn_mfma_f32_16x16x32_bf16(af[mt], bfv[nt], acc[mt][nt], 0, 0, 0);
    }
  };

  // 2-phase pipeline on A only
  stageA(0, 0);
  __syncthreads();              // vmcnt(0) drain: buf0 ready
  #pragma unroll
  for (int t = 1; t < K / 64; t++) {
    stageA(t & 1, t * 64);      // issue next A-tile
    compute((t - 1) & 1, (t - 1) * 64);
    __syncthreads();
  }
  compute((K / 64 - 1) & 1, K - 64);

  if (EPI == 0) {
    #pragma unroll
    for (int mt = 0; mt < 4; mt++)
      #pragma unroll
      for (int nt = 0; nt < 4; nt++) {
        int n = nbase + wn + nt*16 + l15;
        float bv = bias[n];
        #pragma unroll
        for (int r = 0; r < 4; r++) {
          int m = mbase + wm + mt*16 + lg*4 + r;
          outF[(size_t)m * DIMC + n] = acc[mt][nt][r] + bv;
        }
      }
  } else {
    const int which = nbase / DIMC;   // uniform per block: 0=Q 1=K 2=V
    #pragma unroll
    for (int mt = 0; mt < 4; mt++)
      #pragma unroll
      for (int r = 0; r < 4; r++) {
        int m = mbase + wm + mt*16 + lg*4 + r;
        int b = m / NTOK, nn = m - b * NTOK;
        #pragma unroll
        for (int nt = 0; nt < 4; nt++) {
          int n = nbase + wn + nt*16 + l15;
          int nm = n - which * DIMC;
          int h = nm >> 5, d = nm & 31;
          float v = acc[mt][nt][r] + bias[n];
          if (which == 0) {
            Qb[(((size_t)b*NH + h)*NTOK + nn)*HDIM + d] = f2bf(v * SCALE_);
          } else if (which == 1) {
            Kb[(((size_t)b*NH + h)*NTOK + nn)*HDIM + d] = f2bf(v);
          } else {
            Vb[(((size_t)b*NH + h)*HDIM + d)*64 + nn] = f2bf(v); // transposed, padded to 64
          }
        }
      }
  }
}

// ---------------- attention: one block per window, wave handles 3 heads ----------------
__global__ __launch_bounds__(256) void attn_kernel(
    const ushort* __restrict__ Qb, const ushort* __restrict__ Kb,
    const ushort* __restrict__ Vb, const float* __restrict__ comb,
    ushort* __restrict__ Ob)
{
  __shared__ ushort Pl[4][64][72];   // per-wave P buffer, padded
  const int b    = blockIdx.x;
  const int tid  = threadIdx.x;
  const int lane = tid & 63, wv = tid >> 6;
  const int l15  = lane & 15, lg = lane >> 4;
  const int widx = b & (NW - 1);

  for (int hi = 0; hi < 3; hi++) {
    const int h = wv * 3 + hi;
    const ushort* Qh = Qb + ((size_t)b*NH + h) * NTOK * HDIM;
    const ushort* Kh = Kb + ((size_t)b*NH + h) * NTOK * HDIM;
    const ushort* Vh = Vb + ((size_t)b*NH + h) * HDIM * 64;
    const float*  cw = comb + ((size_t)widx*NH + h) * NTOK * NTOK;

    s16x8 qf[4], kf[4];
    #pragma unroll
    for (int t = 0; t < 4; t++) {
      int r = t*16 + l15; r = r > 48 ? 48 : r;
      qf[t] = *(const s16x8*)(Qh + r*HDIM + lg*8);
      kf[t] = *(const s16x8*)(Kh + r*HDIM + lg*8);
    }
    f32x4 s[4][4];
    #pragma unroll
    for (int it = 0; it < 4; it++)
      #pragma unroll
      for (int jt = 0; jt < 4; jt++) s[it][jt] = (f32x4){0.f,0.f,0.f,0.f};
    #pragma unroll
    for (int it = 0; it < 4; it++)
      #pragma unroll
      for (int jt = 0; jt < 4; jt++)
        s[it][jt] = __builtin_amdgcn_mfma_f32_16x16x32_bf16(qf[it], kf[jt], s[it][jt], 0, 0, 0);

    float rmax[4][4];
    #pragma unroll
    for (int it = 0; it < 4; it++)
      #pragma unroll
      for (int r = 0; r < 4; r++) rmax[it][r] = -3.0e38f;
    #pragma unroll
    for (int it = 0; it < 4; it++)
      #pragma unroll
      for (int jt = 0; jt < 4; jt++) {
        int c = jt*16 + l15;
        #pragma unroll
        for (int r = 0; r < 4; r++) {
          int rr = it*16 + lg*4 + r;
          float v;
          if (rr < NTOK && c < NTOK)
            v = s[it][jt][r] + cw[rr*NTOK + c];
          else
            v = -1.0e30f;
          s[it][jt][r] = v;
          rmax[it][r] = fmaxf(rmax[it][r], v);
        }
      }
    #pragma unroll
    for (int it = 0; it < 4; it++)
      #pragma unroll
      for (int r = 0; r < 4; r++)
        #pragma unroll
        for (int x = 1; x < 16; x <<= 1)
          rmax[it][r] = fmaxf(rmax[it][r], __shfl_xor(rmax[it][r], x));

    float rsum[4][4];
    #pragma unroll
    for (int it = 0; it < 4; it++)
      #pragma unroll
      for (int r = 0; r < 4; r++) rsum[it][r] = 0.f;
    #pragma unroll
    for (int it = 0; it < 4; it++)
      #pragma unroll
      for (int jt = 0; jt < 4; jt++)
        #pragma unroll
        for (int r = 0; r < 4; r++) {
          float e = __expf(s[it][jt][r] - rmax[it][r]);
          s[it][jt][r] = e;
          rsum[it][r] += e;
        }
    #pragma unroll
    for (int it = 0; it < 4; it++)
      #pragma unroll
      for (int r = 0; r < 4; r++)
        #pragma unroll
        for (int x = 1; x < 16; x <<= 1)
          rsum[it][r] += __shfl_xor(rsum[it][r], x);

    // P -> LDS (unnormalized bf16); normalization folded into O store
    #pragma unroll
    for (int it = 0; it < 4; it++)
      #pragma unroll
      for (int jt = 0; jt < 4; jt++)
        #pragma unroll
        for (int r = 0; r < 4; r++)
          Pl[wv][it*16 + lg*4 + r][jt*16 + l15] = f2bf(s[it][jt][r]);

    // V^T fragments; zero padded columns in registers (NaN-safe vs poisoned ws)
    s16x8 vf[2][2];
    #pragma unroll
    for (int nt = 0; nt < 2; nt++)
      #pragma unroll
      for (int kk = 0; kk < 2; kk++) {
        int dd = nt*16 + l15;
        int c0 = kk*32 + lg*8;
        s16x8 t = *(const s16x8*)(Vh + dd*64 + c0);
        #pragma unroll
        for (int e = 0; e < 8; e++) if (c0 + e >= NTOK) t[e] = 0;
        vf[nt][kk] = t;
      }

    f32x4 o[4][2];
    #pragma unroll
    for (int it = 0; it < 4; it++)
      #pragma unroll
      for (int nt = 0; nt < 2; nt++) o[it][nt] = (f32x4){0.f,0.f,0.f,0.f};
    #pragma unroll
    for (int it = 0; it < 4; it++)
      #pragma unroll
      for (int kk = 0; kk < 2; kk++) {
        s16x8 pf = *(const s16x8*)&Pl[wv][it*16 + l15][kk*32 + lg*8];
        #pragma unroll
        for (int nt = 0; nt < 2; nt++)
          o[it][nt] = __builtin_amdgcn_mfma_f32_16x16x32_bf16(pf, vf[nt][kk], o[it][nt], 0, 0, 0);
      }

    #pragma unroll
    for (int it = 0; it < 4; it++)
      #pragma unroll
      for (int r = 0; r < 4; r++) {
        int q = it*16 + lg*4 + r;
        if (q < NTOK) {
          float ri = 1.0f / rsum[it][r];
          #pragma unroll
          for (int nt = 0; nt < 2; nt++)
            Ob[((size_t)b*NTOK + q)*DIMC + h*HDIM + nt*16 + l15] = f2bf(o[it][nt][r] * ri);
        }
      }
  }
}

// ---------------- launch ----------------
extern "C" void kernel_launch(void* const* d_in, const int* in_sizes, int n_in,
                              void* d_out, int out_size, void* d_ws, size_t ws_size,
                              hipStream_t stream)
{
  const float* x      = (const float*)d_in[0];
  const float* mask   = (const float*)d_in[1];
  const float* qkv_w  = (const float*)d_in[2];
  const float* qkv_b  = (const float*)d_in[3];
  const float* proj_w = (const float*)d_in[4];
  const float* proj_b = (const float*)d_in[5];
  const float* rtab   = (const float*)d_in[6];
  const int*   ridx   = (const int*)d_in[7];
  float* out = (float*)d_out;

  char* p = (char*)d_ws;
  auto alloc = [&](size_t bytes) { char* r = p; p += (bytes + 255) & ~(size_t)255; return r; };
  ushort* xb = (ushort*)alloc((size_t)BQ*NTOK*DIMC*2);      // 154.1 MB bf16 x
  ushort* Qb = (ushort*)alloc((size_t)BQ*NH*NTOK*HDIM*2);   // 154.1 MB
  ushort* Kb = (ushort*)alloc((size_t)BQ*NH*NTOK*HDIM*2);   // 154.1 MB
  ushort* Vb = (ushort*)alloc((size_t)BQ*NH*HDIM*64*2);     // 201.3 MB (transposed, padded)
  ushort* Ob = (ushort*)alloc((size_t)BQ*NTOK*DIMC*2);      // 154.1 MB
  ushort* qw = (ushort*)alloc((size_t)3*DIMC*DIMC*2);
  ushort* pw = (ushort*)alloc((size_t)DIMC*DIMC*2);
  float*  cb = (float*)alloc((size_t)NW*NH*NTOK*NTOK*4);    // 7.4 MB combined bias+mask

  const int n8 = BQ*NTOK*DIMC/8;
  cast_x_kernel<<<2048, 256, 0, stream>>>(x, xb, n8);
  prep_kernel<<<(PREP_N1 + PREP_N2 + PREP_N3 + 255)/256, 256, 0, stream>>>(
      qkv_w, proj_w, rtab, ridx, mask, qw, pw, cb);

  // QKV: M=200704, N=1152, K=384 -> 1568*9 = 14112 blocks (div by 8)
  gemm_bt_kernel<1, DIMC, 9><<<14112, 256, 0, stream>>>(xb, qw, qkv_b, nullptr, Qb, Kb, Vb);

  attn_kernel<<<BQ, 256, 0, stream>>>(Qb, Kb, Vb, cb, Ob);

  // proj: M=200704, N=384 -> 1568*3 = 4704 blocks (div by 8)
  gemm_bt_kernel<0, DIMC, 3><<<4704, 256, 0, stream>>>(Ob, pw, proj_b, out, nullptr, nullptr, nullptr);
}

// Round 6
// 821.184 us; speedup vs baseline: 1.3163x; 1.3163x over previous
//
#include <hip/hip_runtime.h>
#include <hip/hip_bf16.h>

typedef __attribute__((ext_vector_type(4))) float  f32x4;
typedef __attribute__((ext_vector_type(8))) short  s16x8;

#define DEVI static __device__ __forceinline__

constexpr int   BQ    = 4096;   // windows
constexpr int   NTOK  = 49;     // tokens per window
constexpr int   DIMC  = 384;
constexpr int   NH    = 12;
constexpr int   HDIM  = 32;
constexpr int   NW    = 64;
constexpr int   QKVN  = 3 * DIMC;  // 1152
constexpr float SCALE_ = 0.17677669529663687f; // 32^-0.5

DEVI ushort f2bf(float f) {
  union { float f; unsigned u; } v; v.f = f;
  unsigned r = v.u + 0x7fffu + ((v.u >> 16) & 1u);
  return (ushort)(r >> 16);
}

// async global->LDS, 16B per lane; LDS dest = wave-uniform base + lane*16
DEVI void async_ld16(const ushort* g, const ushort* l) {
  auto gp = reinterpret_cast<const __attribute__((address_space(1))) unsigned int*>(
      reinterpret_cast<uintptr_t>(g));
  auto lp = reinterpret_cast<__attribute__((address_space(3))) unsigned int*>(
      reinterpret_cast<uintptr_t>(l));
  __builtin_amdgcn_global_load_lds(gp, lp, 16, 0, 0);
}

// ---------------- prep kernels ----------------
__global__ void cast_x_kernel(const float* __restrict__ x, ushort* __restrict__ o, int n8) {
  int i = blockIdx.x * 256 + threadIdx.x;
  const int stride = gridDim.x * 256;
  for (; i < n8; i += stride) {
    f32x4 a = *(const f32x4*)(x + (size_t)i * 8);
    f32x4 b = *(const f32x4*)(x + (size_t)i * 8 + 4);
    s16x8 v;
    v[0] = (short)f2bf(a[0]); v[1] = (short)f2bf(a[1]);
    v[2] = (short)f2bf(a[2]); v[3] = (short)f2bf(a[3]);
    v[4] = (short)f2bf(b[0]); v[5] = (short)f2bf(b[1]);
    v[6] = (short)f2bf(b[2]); v[7] = (short)f2bf(b[3]);
    *(s16x8*)(o + (size_t)i * 8) = v;
  }
}

// one kernel: cast qkv_w (Q rows pre-scaled by SCALE_), cast proj_w,
// build combined bias+mask table, build scaled qkv bias
constexpr int PREP_N1 = QKVN * DIMC;               // 442368 qw
constexpr int PREP_N2 = DIMC * DIMC;               // 147456 pw
constexpr int PREP_N3 = NW * NH * NTOK * NTOK;     // 1843968 comb
constexpr int PREP_N4 = QKVN;                      // 1152 scaled bias
__global__ void prep_kernel(const float* __restrict__ qkv_w, const float* __restrict__ proj_w,
                            const float* __restrict__ tab, const int* __restrict__ idx,
                            const float* __restrict__ mask, const float* __restrict__ qkv_b,
                            ushort* __restrict__ qw, ushort* __restrict__ pw,
                            float* __restrict__ comb, float* __restrict__ qbias) {
  int i = blockIdx.x * 256 + threadIdx.x;
  if (i < PREP_N1) {
    int n = i / DIMC;                       // output channel; n<384 = Q -> fold SCALE
    float sc = (n < DIMC) ? SCALE_ : 1.0f;
    qw[i] = f2bf(qkv_w[i] * sc);
  } else if (i < PREP_N1 + PREP_N2) {
    int j = i - PREP_N1;
    pw[j] = f2bf(proj_w[j]);
  } else if (i < PREP_N1 + PREP_N2 + PREP_N3) {
    int j = i - PREP_N1 - PREP_N2;
    int rc = j % (NTOK * NTOK);
    int wh = j / (NTOK * NTOK);
    int h = wh % NH, w = wh / NH;
    comb[j] = tab[idx[rc] * NH + h] + mask[(size_t)w * NTOK * NTOK + rc];
  } else if (i < PREP_N1 + PREP_N2 + PREP_N3 + PREP_N4) {
    int j = i - PREP_N1 - PREP_N2 - PREP_N3;
    qbias[j] = qkv_b[j] * ((j < DIMC) ? SCALE_ : 1.0f);
  }
}

// ---------------- GEMM: C = A * B^T (+bias), bf16 MFMA ----------------
// BK=32 double-buffered A+B (32 KB), true 2-phase: stage(t+1) || compute(t).
// At BK=32 a row is 64B so fragment ds_read_b128 are naturally conflict-free.
// EPI 0: fp32 C + bias -> outF[m*NB*128+n]  (direct coalesced stores)
// EPI 1: bf16 C + bias -> outBF[m][NB*128] via LDS-restage (coalesced 16B stores)
template<int EPI, int K, int NB>
__global__ __launch_bounds__(256) void gemm_bt_kernel(
    const ushort* __restrict__ Ap, const ushort* __restrict__ Bp,
    const float* __restrict__ bias, float* __restrict__ outF,
    ushort* __restrict__ outBF)
{
  struct MB { ushort A[2][128 * 32]; ushort B[2][128 * 32]; };
  union ShU { MB mb; ushort Ct[128 * 136]; };
  __shared__ ShU sh;   // 34 KB

  const int tid  = threadIdx.x;
  const int lane = tid & 63;
  const int wv   = tid >> 6;
  const int wm   = (wv >> 1) * 64, wn = (wv & 1) * 64;
  const int l15  = lane & 15, lg = lane >> 4;
  constexpr int NT = NB * 128;          // output row width

  // bijective XCD-chunked swizzle (gridDim.x divisible by 8)
  const int chunk = gridDim.x >> 3;
  const int wgid  = (blockIdx.x & 7) * chunk + (blockIdx.x >> 3);
  const int nbase = (wgid % NB) * 128;
  const int mbase = (wgid / NB) * 128;

  const int srow = lane >> 2;           // 16 rows per gload issue
  const int scol = (lane & 3) * 8;      // 4 chunks of 8 bf16 per row

  const ushort* Abase = Ap + (size_t)(mbase + wv * 32 + srow) * K + scol;
  const ushort* Bbase = Bp + (size_t)(nbase + wv * 32 + srow) * K + scol;

  f32x4 acc[4][4];
  #pragma unroll
  for (int i = 0; i < 4; i++)
    #pragma unroll
    for (int j = 0; j < 4; j++) acc[i][j] = (f32x4){0.f, 0.f, 0.f, 0.f};

  auto stage = [&](int buf, int k0) {
    #pragma unroll
    for (int i = 0; i < 2; i++) {
      async_ld16(Abase + (size_t)i * 16 * K + k0, &sh.mb.A[buf][(wv * 32 + i * 16) * 32]);
      async_ld16(Bbase + (size_t)i * 16 * K + k0, &sh.mb.B[buf][(wv * 32 + i * 16) * 32]);
    }
  };
  auto compute = [&](int buf) {
    s16x8 af[4], bfv[4];
    #pragma unroll
    for (int t = 0; t < 4; t++) af[t]  = *(const s16x8*)&sh.mb.A[buf][(wm + t*16 + l15) * 32 + lg*8];
    #pragma unroll
    for (int t = 0; t < 4; t++) bfv[t] = *(const s16x8*)&sh.mb.B[buf][(wn + t*16 + l15) * 32 + lg*8];
    #pragma unroll
    for (int mt = 0; mt < 4; mt++)
      #pragma unroll
      for (int nt = 0; nt < 4; nt++)
        acc[mt][nt] = __builtin_amdgcn_mfma_f32_16x16x32_bf16(af[mt], bfv[nt], acc[mt][nt], 0, 0, 0);
  };

  constexpr int NSTEP = K / 32;
  stage(0, 0);
  __syncthreads();                      // buf0 landed
  #pragma unroll
  for (int t = 1; t < NSTEP; t++) {
    stage(t & 1, t * 32);               // prefetch next tile into other buffer
    compute((t - 1) & 1);               // MFMA on current
    __syncthreads();                    // reads done + next tile landed
  }
  compute((NSTEP - 1) & 1);

  if (EPI == 0) {
    #pragma unroll
    for (int mt = 0; mt < 4; mt++)
      #pragma unroll
      for (int nt = 0; nt < 4; nt++) {
        int n = nbase + wn + nt*16 + l15;
        float bv = bias[n];
        #pragma unroll
        for (int r = 0; r < 4; r++) {
          int m = mbase + wm + mt*16 + lg*4 + r;
          outF[(size_t)m * NT + n] = acc[mt][nt][r] + bv;
        }
      }
  } else {
    // restage through LDS ([128][136] padded) -> coalesced 16B row stores
    __syncthreads();                    // all LDS reads done before overwrite
    float bv[4];
    #pragma unroll
    for (int nt = 0; nt < 4; nt++) bv[nt] = bias[nbase + wn + nt*16 + l15];
    #pragma unroll
    for (int mt = 0; mt < 4; mt++)
      #pragma unroll
      for (int nt = 0; nt < 4; nt++) {
        int col = wn + nt*16 + l15;
        #pragma unroll
        for (int r = 0; r < 4; r++)
          sh.Ct[(wm + mt*16 + lg*4 + r) * 136 + col] = f2bf(acc[mt][nt][r] + bv[nt]);
      }
    __syncthreads();
    #pragma unroll
    for (int i = 0; i < 8; i++) {
      int c = tid + i * 256;            // 2048 chunks of 16B
      int row = c >> 4, col8 = (c & 15) * 8;
      *(s16x8*)(outBF + (size_t)(mbase + row) * NT + nbase + col8) =
          *(const s16x8*)&sh.Ct[row * 136 + col8];
    }
  }
}

// ---------------- attention: one block per window, wave handles 3 heads ----------------
// Q/K/V read from plain QKV[m][1152] (head slice = one 64B line);
// V transposed per (wave,head) through a small LDS buffer.
__global__ __launch_bounds__(256) void attn_kernel(
    const ushort* __restrict__ QKVb, const float* __restrict__ comb,
    ushort* __restrict__ Ob)
{
  __shared__ ushort Pl[4][64][72];   // per-wave P buffer
  __shared__ ushort Vt[4][32][72];   // per-wave V^T buffer
  const int b    = blockIdx.x;
  const int tid  = threadIdx.x;
  const int lane = tid & 63, wv = tid >> 6;
  const int l15  = lane & 15, lg = lane >> 4;
  const int widx = b & (NW - 1);

  for (int hi = 0; hi < 3; hi++) {
    const int h = wv * 3 + hi;
    const ushort* Wq = QKVb + (size_t)b * NTOK * QKVN + h * HDIM;   // Q slice (pre-scaled)
    const float*  cw = comb + ((size_t)widx*NH + h) * NTOK * NTOK;

    s16x8 qf[4], kf[4];
    #pragma unroll
    for (int t = 0; t < 4; t++) {
      int r = t*16 + l15; r = r > 48 ? 48 : r;
      qf[t] = *(const s16x8*)(Wq + (size_t)r*QKVN + lg*8);
      kf[t] = *(const s16x8*)(Wq + DIMC + (size_t)r*QKVN + lg*8);
    }

    // V transpose: lane nn reads its V row (4x16B), scatters to Vt[d][nn]
    {
      s16x8 vrow[4];
      #pragma unroll
      for (int c = 0; c < 4; c++) {
        if (lane < NTOK)
          vrow[c] = *(const s16x8*)(Wq + 2*DIMC + (size_t)lane*QKVN + c*8);
        else
          vrow[c] = (s16x8){0,0,0,0,0,0,0,0};
      }
      #pragma unroll
      for (int c = 0; c < 4; c++)
        #pragma unroll
        for (int e = 0; e < 8; e++)
          Vt[wv][c*8 + e][lane] = (ushort)vrow[c][e];
    }

    f32x4 s[4][4];
    #pragma unroll
    for (int it = 0; it < 4; it++)
      #pragma unroll
      for (int jt = 0; jt < 4; jt++) s[it][jt] = (f32x4){0.f,0.f,0.f,0.f};
    #pragma unroll
    for (int it = 0; it < 4; it++)
      #pragma unroll
      for (int jt = 0; jt < 4; jt++)
        s[it][jt] = __builtin_amdgcn_mfma_f32_16x16x32_bf16(qf[it], kf[jt], s[it][jt], 0, 0, 0);

    float rmax[4][4];
    #pragma unroll
    for (int it = 0; it < 4; it++)
      #pragma unroll
      for (int r = 0; r < 4; r++) rmax[it][r] = -3.0e38f;
    #pragma unroll
    for (int it = 0; it < 4; it++)
      #pragma unroll
      for (int jt = 0; jt < 4; jt++) {
        int c = jt*16 + l15;
        #pragma unroll
        for (int r = 0; r < 4; r++) {
          int rr = it*16 + lg*4 + r;
          float v;
          if (rr < NTOK && c < NTOK)
            v = s[it][jt][r] + cw[rr*NTOK + c];
          else
            v = -1.0e30f;
          s[it][jt][r] = v;
          rmax[it][r] = fmaxf(rmax[it][r], v);
        }
      }
    #pragma unroll
    for (int it = 0; it < 4; it++)
      #pragma unroll
      for (int r = 0; r < 4; r++)
        #pragma unroll
        for (int x = 1; x < 16; x <<= 1)
          rmax[it][r] = fmaxf(rmax[it][r], __shfl_xor(rmax[it][r], x));

    float rsum[4][4];
    #pragma unroll
    for (int it = 0; it < 4; it++)
      #pragma unroll
      for (int r = 0; r < 4; r++) rsum[it][r] = 0.f;
    #pragma unroll
    for (int it = 0; it < 4; it++)
      #pragma unroll
      for (int jt = 0; jt < 4; jt++)
        #pragma unroll
        for (int r = 0; r < 4; r++) {
          float e = __expf(s[it][jt][r] - rmax[it][r]);
          s[it][jt][r] = e;
          rsum[it][r] += e;
        }
    #pragma unroll
    for (int it = 0; it < 4; it++)
      #pragma unroll
      for (int r = 0; r < 4; r++)
        #pragma unroll
        for (int x = 1; x < 16; x <<= 1)
          rsum[it][r] += __shfl_xor(rsum[it][r], x);

    // P -> LDS (unnormalized bf16); normalization folded into O store
    #pragma unroll
    for (int it = 0; it < 4; it++)
      #pragma unroll
      for (int jt = 0; jt < 4; jt++)
        #pragma unroll
        for (int r = 0; r < 4; r++)
          Pl[wv][it*16 + lg*4 + r][jt*16 + l15] = f2bf(s[it][jt][r]);

    // V^T fragments from Vt (pad-72: balanced banks)
    s16x8 vf[2][2];
    #pragma unroll
    for (int nt = 0; nt < 2; nt++)
      #pragma unroll
      for (int kk = 0; kk < 2; kk++)
        vf[nt][kk] = *(const s16x8*)&Vt[wv][nt*16 + l15][kk*32 + lg*8];

    f32x4 o[4][2];
    #pragma unroll
    for (int it = 0; it < 4; it++)
      #pragma unroll
      for (int nt = 0; nt < 2; nt++) o[it][nt] = (f32x4){0.f,0.f,0.f,0.f};
    #pragma unroll
    for (int it = 0; it < 4; it++)
      #pragma unroll
      for (int kk = 0; kk < 2; kk++) {
        s16x8 pf = *(const s16x8*)&Pl[wv][it*16 + l15][kk*32 + lg*8];
        #pragma unroll
        for (int nt = 0; nt < 2; nt++)
          o[it][nt] = __builtin_amdgcn_mfma_f32_16x16x32_bf16(pf, vf[nt][kk], o[it][nt], 0, 0, 0);
      }

    #pragma unroll
    for (int it = 0; it < 4; it++)
      #pragma unroll
      for (int r = 0; r < 4; r++) {
        int q = it*16 + lg*4 + r;
        if (q < NTOK) {
          float ri = 1.0f / rsum[it][r];
          #pragma unroll
          for (int nt = 0; nt < 2; nt++)
            Ob[((size_t)b*NTOK + q)*DIMC + h*HDIM + nt*16 + l15] = f2bf(o[it][nt][r] * ri);
        }
      }
  }
}

// ---------------- launch ----------------
extern "C" void kernel_launch(void* const* d_in, const int* in_sizes, int n_in,
                              void* d_out, int out_size, void* d_ws, size_t ws_size,
                              hipStream_t stream)
{
  const float* x      = (const float*)d_in[0];
  const float* mask   = (const float*)d_in[1];
  const float* qkv_w  = (const float*)d_in[2];
  const float* qkv_b  = (const float*)d_in[3];
  const float* proj_w = (const float*)d_in[4];
  const float* proj_b = (const float*)d_in[5];
  const float* rtab   = (const float*)d_in[6];
  const int*   ridx   = (const int*)d_in[7];
  float* out = (float*)d_out;

  char* p = (char*)d_ws;
  auto alloc = [&](size_t bytes) { char* r = p; p += (bytes + 255) & ~(size_t)255; return r; };
  ushort* xb    = (ushort*)alloc((size_t)BQ*NTOK*DIMC*2);    // 154.1 MB bf16 x
  ushort* QKVb  = (ushort*)alloc((size_t)BQ*NTOK*QKVN*2);    // 462.4 MB QKV rows
  ushort* Ob    = (ushort*)alloc((size_t)BQ*NTOK*DIMC*2);    // 154.1 MB
  ushort* qw    = (ushort*)alloc((size_t)QKVN*DIMC*2);
  ushort* pw    = (ushort*)alloc((size_t)DIMC*DIMC*2);
  float*  cb    = (float*)alloc((size_t)NW*NH*NTOK*NTOK*4);  // 7.4 MB bias+mask
  float*  qbias = (float*)alloc((size_t)QKVN*4);

  const int n8 = BQ*NTOK*DIMC/8;
  cast_x_kernel<<<2048, 256, 0, stream>>>(x, xb, n8);
  prep_kernel<<<(PREP_N1+PREP_N2+PREP_N3+PREP_N4 + 255)/256, 256, 0, stream>>>(
      qkv_w, proj_w, rtab, ridx, mask, qkv_b, qw, pw, cb, qbias);

  // QKV: M=200704, N=1152, K=384 -> 1568*9 = 14112 blocks (div by 8)
  gemm_bt_kernel<1, DIMC, 9><<<14112, 256, 0, stream>>>(xb, qw, qbias, nullptr, QKVb);

  attn_kernel<<<BQ, 256, 0, stream>>>(QKVb, cb, Ob);

  // proj: M=200704, N=384 -> 1568*3 = 4704 blocks (div by 8)
  gemm_bt_kernel<0, DIMC, 3><<<4704, 256, 0, stream>>>(Ob, pw, proj_b, out, nullptr);
}

// Round 7
// 810.715 us; speedup vs baseline: 1.3333x; 1.0129x over previous
//
#include <hip/hip_runtime.h>
#include <hip/hip_bf16.h>

typedef __attribute__((ext_vector_type(4))) float  f32x4;
typedef __attribute__((ext_vector_type(8))) short  s16x8;

#define DEVI static __device__ __forceinline__

constexpr int   BQ    = 4096;   // windows
constexpr int   NTOK  = 49;     // tokens per window
constexpr int   DIMC  = 384;
constexpr int   NH    = 12;
constexpr int   HDIM  = 32;
constexpr int   NW    = 64;
constexpr int   QKVN  = 3 * DIMC;  // 1152
constexpr float SCALE_ = 0.17677669529663687f; // 32^-0.5

DEVI ushort f2bf(float f) {
  union { float f; unsigned u; } v; v.f = f;
  unsigned r = v.u + 0x7fffu + ((v.u >> 16) & 1u);
  return (ushort)(r >> 16);
}

// async global->LDS, 16B per lane; LDS dest = wave-uniform base + lane*16
DEVI void async_ld16(const ushort* g, const ushort* l) {
  auto gp = reinterpret_cast<const __attribute__((address_space(1))) unsigned int*>(
      reinterpret_cast<uintptr_t>(g));
  auto lp = reinterpret_cast<__attribute__((address_space(3))) unsigned int*>(
      reinterpret_cast<uintptr_t>(l));
  __builtin_amdgcn_global_load_lds(gp, lp, 16, 0, 0);
}

// ---------------- prep kernels ----------------
__global__ void cast_x_kernel(const float* __restrict__ x, ushort* __restrict__ o, int n8) {
  int i = blockIdx.x * 256 + threadIdx.x;
  const int stride = gridDim.x * 256;
  for (; i < n8; i += stride) {
    f32x4 a = *(const f32x4*)(x + (size_t)i * 8);
    f32x4 b = *(const f32x4*)(x + (size_t)i * 8 + 4);
    s16x8 v;
    v[0] = (short)f2bf(a[0]); v[1] = (short)f2bf(a[1]);
    v[2] = (short)f2bf(a[2]); v[3] = (short)f2bf(a[3]);
    v[4] = (short)f2bf(b[0]); v[5] = (short)f2bf(b[1]);
    v[6] = (short)f2bf(b[2]); v[7] = (short)f2bf(b[3]);
    *(s16x8*)(o + (size_t)i * 8) = v;
  }
}

// prep: cast qkv_w (Q rows pre-scaled), cast proj_w, build MFMA-layout
// bias+mask table combP[w][h][tile=it*4+jt][lane] (f32x4 over r), scaled qkv bias.
// combP pad entries (rr>=49 || c>=49) are -1e30 -> no bounds checks in attn.
constexpr int PREP_N1 = QKVN * DIMC;               // 442368 qw
constexpr int PREP_N2 = DIMC * DIMC;               // 147456 pw
constexpr int PREP_N3 = NW * NH * 16 * 64;         // 786432 combP f32x4 units
constexpr int PREP_N4 = QKVN;                      // 1152 scaled bias
__global__ void prep_kernel(const float* __restrict__ qkv_w, const float* __restrict__ proj_w,
                            const float* __restrict__ tab, const int* __restrict__ idx,
                            const float* __restrict__ mask, const float* __restrict__ qkv_b,
                            ushort* __restrict__ qw, ushort* __restrict__ pw,
                            float* __restrict__ combP, float* __restrict__ qbias) {
  int i = blockIdx.x * 256 + threadIdx.x;
  if (i < PREP_N1) {
    int n = i / DIMC;                       // output channel; n<384 = Q -> fold SCALE
    float sc = (n < DIMC) ? SCALE_ : 1.0f;
    qw[i] = f2bf(qkv_w[i] * sc);
  } else if (i < PREP_N1 + PREP_N2) {
    int j = i - PREP_N1;
    pw[j] = f2bf(proj_w[j]);
  } else if (i < PREP_N1 + PREP_N2 + PREP_N3) {
    int j = i - PREP_N1 - PREP_N2;          // [w][h][tile][lane]
    int lane = j & 63;
    int tile = (j >> 6) & 15;
    int wh   = j >> 10;
    int h = wh % NH, w = wh / NH;
    int it = tile >> 2, jt = tile & 3;
    int c = jt * 16 + (lane & 15);
    f32x4 v;
    #pragma unroll
    for (int r = 0; r < 4; r++) {
      int rr = it * 16 + (lane >> 4) * 4 + r;
      v[r] = (rr < NTOK && c < NTOK)
           ? tab[idx[rr * NTOK + c] * NH + h] + mask[(size_t)w * NTOK * NTOK + rr * NTOK + c]
           : -1.0e30f;
    }
    ((f32x4*)combP)[j] = v;
  } else if (i < PREP_N1 + PREP_N2 + PREP_N3 + PREP_N4) {
    int j = i - PREP_N1 - PREP_N2 - PREP_N3;
    qbias[j] = qkv_b[j] * ((j < DIMC) ? SCALE_ : 1.0f);
  }
}

// ---------------- GEMM: C = A * B^T (+bias), bf16 MFMA ----------------
// BK=32 double-buffered A+B (32 KB), true 2-phase: stage(t+1) || compute(t).
// At BK=32 a row is 64B so fragment ds_read_b128 are naturally conflict-free.
// EPI 0: fp32 C + bias -> outF[m*NB*128+n]  (direct coalesced stores)
// EPI 1: bf16 C + bias -> outBF[m][NB*128] via LDS-restage (coalesced 16B stores)
template<int EPI, int K, int NB>
__global__ __launch_bounds__(256) void gemm_bt_kernel(
    const ushort* __restrict__ Ap, const ushort* __restrict__ Bp,
    const float* __restrict__ bias, float* __restrict__ outF,
    ushort* __restrict__ outBF)
{
  struct MB { ushort A[2][128 * 32]; ushort B[2][128 * 32]; };
  union ShU { MB mb; ushort Ct[128 * 136]; };
  __shared__ ShU sh;   // 34 KB

  const int tid  = threadIdx.x;
  const int lane = tid & 63;
  const int wv   = tid >> 6;
  const int wm   = (wv >> 1) * 64, wn = (wv & 1) * 64;
  const int l15  = lane & 15, lg = lane >> 4;
  constexpr int NT = NB * 128;          // output row width

  // bijective XCD-chunked swizzle (gridDim.x divisible by 8)
  const int chunk = gridDim.x >> 3;
  const int wgid  = (blockIdx.x & 7) * chunk + (blockIdx.x >> 3);
  const int nbase = (wgid % NB) * 128;
  const int mbase = (wgid / NB) * 128;

  const int srow = lane >> 2;           // 16 rows per gload issue
  const int scol = (lane & 3) * 8;      // 4 chunks of 8 bf16 per row

  const ushort* Abase = Ap + (size_t)(mbase + wv * 32 + srow) * K + scol;
  const ushort* Bbase = Bp + (size_t)(nbase + wv * 32 + srow) * K + scol;

  f32x4 acc[4][4];
  #pragma unroll
  for (int i = 0; i < 4; i++)
    #pragma unroll
    for (int j = 0; j < 4; j++) acc[i][j] = (f32x4){0.f, 0.f, 0.f, 0.f};

  auto stage = [&](int buf, int k0) {
    #pragma unroll
    for (int i = 0; i < 2; i++) {
      async_ld16(Abase + (size_t)i * 16 * K + k0, &sh.mb.A[buf][(wv * 32 + i * 16) * 32]);
      async_ld16(Bbase + (size_t)i * 16 * K + k0, &sh.mb.B[buf][(wv * 32 + i * 16) * 32]);
    }
  };
  auto compute = [&](int buf) {
    s16x8 af[4], bfv[4];
    #pragma unroll
    for (int t = 0; t < 4; t++) af[t]  = *(const s16x8*)&sh.mb.A[buf][(wm + t*16 + l15) * 32 + lg*8];
    #pragma unroll
    for (int t = 0; t < 4; t++) bfv[t] = *(const s16x8*)&sh.mb.B[buf][(wn + t*16 + l15) * 32 + lg*8];
    #pragma unroll
    for (int mt = 0; mt < 4; mt++)
      #pragma unroll
      for (int nt = 0; nt < 4; nt++)
        acc[mt][nt] = __builtin_amdgcn_mfma_f32_16x16x32_bf16(af[mt], bfv[nt], acc[mt][nt], 0, 0, 0);
  };

  constexpr int NSTEP = K / 32;
  stage(0, 0);
  __syncthreads();                      // buf0 landed
  #pragma unroll
  for (int t = 1; t < NSTEP; t++) {
    stage(t & 1, t * 32);               // prefetch next tile into other buffer
    compute((t - 1) & 1);               // MFMA on current
    __syncthreads();                    // reads done + next tile landed
  }
  compute((NSTEP - 1) & 1);

  if (EPI == 0) {
    #pragma unroll
    for (int mt = 0; mt < 4; mt++)
      #pragma unroll
      for (int nt = 0; nt < 4; nt++) {
        int n = nbase + wn + nt*16 + l15;
        float bv = bias[n];
        #pragma unroll
        for (int r = 0; r < 4; r++) {
          int m = mbase + wm + mt*16 + lg*4 + r;
          outF[(size_t)m * NT + n] = acc[mt][nt][r] + bv;
        }
      }
  } else {
    // restage through LDS ([128][136] padded) -> coalesced 16B row stores
    __syncthreads();                    // all LDS reads done before overwrite
    float bv[4];
    #pragma unroll
    for (int nt = 0; nt < 4; nt++) bv[nt] = bias[nbase + wn + nt*16 + l15];
    #pragma unroll
    for (int mt = 0; mt < 4; mt++)
      #pragma unroll
      for (int nt = 0; nt < 4; nt++) {
        int col = wn + nt*16 + l15;
        #pragma unroll
        for (int r = 0; r < 4; r++)
          sh.Ct[(wm + mt*16 + lg*4 + r) * 136 + col] = f2bf(acc[mt][nt][r] + bv[nt]);
      }
    __syncthreads();
    #pragma unroll
    for (int i = 0; i < 8; i++) {
      int c = tid + i * 256;            // 2048 chunks of 16B
      int row = c >> 4, col8 = (c & 15) * 8;
      *(s16x8*)(outBF + (size_t)(mbase + row) * NT + nbase + col8) =
          *(const s16x8*)&sh.Ct[row * 136 + col8];
    }
  }
}

// ---------------- attention ----------------
// One block per window; wave handles 3 heads sequentially.
// Q/K/V from plain QKV[m][1152]; bias+mask from combP (MFMA-layout f32x4,
// pad entries -1e30 -> zero branches). Per-wave LDS buffer time-shared:
// V^T in rows 0..31 (consumed into vf regs), then P overwrites it.
__global__ __launch_bounds__(256, 4) void attn_kernel(
    const ushort* __restrict__ QKVb, const float* __restrict__ combP,
    ushort* __restrict__ Ob)
{
  __shared__ ushort PV[4][64][72];   // 36.9 KB: per-wave V^T (rows 0..31) then P
  const int b    = blockIdx.x;
  const int tid  = threadIdx.x;
  const int lane = tid & 63, wv = tid >> 6;
  const int l15  = lane & 15, lg = lane >> 4;
  const int widx = b & (NW - 1);

  for (int hi = 0; hi < 3; hi++) {
    const int h = wv * 3 + hi;
    const ushort* Wq = QKVb + (size_t)b * NTOK * QKVN + h * HDIM;   // Q slice (pre-scaled)
    const f32x4*  cp = (const f32x4*)combP + ((size_t)widx * NH + h) * (16 * 64) + lane;

    s16x8 qf[4], kf[4];
    #pragma unroll
    for (int t = 0; t < 4; t++) {
      int r = t*16 + l15; r = r > 48 ? 48 : r;
      qf[t] = *(const s16x8*)(Wq + (size_t)r*QKVN + lg*8);
      kf[t] = *(const s16x8*)(Wq + DIMC + (size_t)r*QKVN + lg*8);
    }

    // V rows -> V^T in PV rows 0..31 (lane = token, row = channel)
    {
      s16x8 vrow[4];
      #pragma unroll
      for (int c = 0; c < 4; c++)
        vrow[c] = (lane < NTOK) ? *(const s16x8*)(Wq + 2*DIMC + (size_t)lane*QKVN + c*8)
                                : (s16x8){0,0,0,0,0,0,0,0};
      #pragma unroll
      for (int c = 0; c < 4; c++)
        #pragma unroll
        for (int e = 0; e < 8; e++)
          PV[wv][c*8 + e][lane] = (ushort)vrow[c][e];
    }

    f32x4 s[4][4];
    #pragma unroll
    for (int it = 0; it < 4; it++)
      #pragma unroll
      for (int jt = 0; jt < 4; jt++) s[it][jt] = (f32x4){0.f,0.f,0.f,0.f};
    #pragma unroll
    for (int it = 0; it < 4; it++)
      #pragma unroll
      for (int jt = 0; jt < 4; jt++)
        s[it][jt] = __builtin_amdgcn_mfma_f32_16x16x32_bf16(qf[it], kf[jt], s[it][jt], 0, 0, 0);

    // bias+mask add (branch-free) + row max
    float rmax[4][4];
    #pragma unroll
    for (int it = 0; it < 4; it++)
      #pragma unroll
      for (int r = 0; r < 4; r++) rmax[it][r] = -3.0e38f;
    #pragma unroll
    for (int it = 0; it < 4; it++)
      #pragma unroll
      for (int jt = 0; jt < 4; jt++) {
        f32x4 cadd = cp[(it*4 + jt) * 64];
        #pragma unroll
        for (int r = 0; r < 4; r++) {
          float v = s[it][jt][r] + cadd[r];
          s[it][jt][r] = v;
          rmax[it][r] = fmaxf(rmax[it][r], v);
        }
      }
    #pragma unroll
    for (int it = 0; it < 4; it++)
      #pragma unroll
      for (int r = 0; r < 4; r++)
        #pragma unroll
        for (int x = 1; x < 16; x <<= 1)
          rmax[it][r] = fmaxf(rmax[it][r], __shfl_xor(rmax[it][r], x));

    float rsum[4][4];
    #pragma unroll
    for (int it = 0; it < 4; it++)
      #pragma unroll
      for (int r = 0; r < 4; r++) rsum[it][r] = 0.f;
    #pragma unroll
    for (int it = 0; it < 4; it++)
      #pragma unroll
      for (int jt = 0; jt < 4; jt++)
        #pragma unroll
        for (int r = 0; r < 4; r++) {
          float e = __expf(s[it][jt][r] - rmax[it][r]);
          s[it][jt][r] = e;
          rsum[it][r] += e;
        }
    #pragma unroll
    for (int it = 0; it < 4; it++)
      #pragma unroll
      for (int r = 0; r < 4; r++)
        #pragma unroll
        for (int x = 1; x < 16; x <<= 1)
          rsum[it][r] += __shfl_xor(rsum[it][r], x);

    // consume V^T into regs BEFORE P overwrites the buffer
    s16x8 vf[2][2];
    #pragma unroll
    for (int nt = 0; nt < 2; nt++)
      #pragma unroll
      for (int kk = 0; kk < 2; kk++)
        vf[nt][kk] = *(const s16x8*)&PV[wv][nt*16 + l15][kk*32 + lg*8];
    asm volatile("s_waitcnt lgkmcnt(0)" ::: "memory");   // vf data in regs
    __builtin_amdgcn_sched_barrier(0);                   // don't sink P writes above

    // P -> LDS (unnormalized bf16); normalization folded into O store
    #pragma unroll
    for (int it = 0; it < 4; it++)
      #pragma unroll
      for (int jt = 0; jt < 4; jt++)
        #pragma unroll
        for (int r = 0; r < 4; r++)
          PV[wv][it*16 + lg*4 + r][jt*16 + l15] = f2bf(s[it][jt][r]);

    f32x4 o[4][2];
    #pragma unroll
    for (int it = 0; it < 4; it++)
      #pragma unroll
      for (int nt = 0; nt < 2; nt++) o[it][nt] = (f32x4){0.f,0.f,0.f,0.f};
    #pragma unroll
    for (int it = 0; it < 4; it++)
      #pragma unroll
      for (int kk = 0; kk < 2; kk++) {
        s16x8 pf = *(const s16x8*)&PV[wv][it*16 + l15][kk*32 + lg*8];
        #pragma unroll
        for (int nt = 0; nt < 2; nt++)
          o[it][nt] = __builtin_amdgcn_mfma_f32_16x16x32_bf16(pf, vf[nt][kk], o[it][nt], 0, 0, 0);
      }

    #pragma unroll
    for (int it = 0; it < 4; it++)
      #pragma unroll
      for (int r = 0; r < 4; r++) {
        int q = it*16 + lg*4 + r;
        if (q < NTOK) {
          float ri = 1.0f / rsum[it][r];
          #pragma unroll
          for (int nt = 0; nt < 2; nt++)
            Ob[((size_t)b*NTOK + q)*DIMC + h*HDIM + nt*16 + l15] = f2bf(o[it][nt][r] * ri);
        }
      }
  }
}

// ---------------- launch ----------------
extern "C" void kernel_launch(void* const* d_in, const int* in_sizes, int n_in,
                              void* d_out, int out_size, void* d_ws, size_t ws_size,
                              hipStream_t stream)
{
  const float* x      = (const float*)d_in[0];
  const float* mask   = (const float*)d_in[1];
  const float* qkv_w  = (const float*)d_in[2];
  const float* qkv_b  = (const float*)d_in[3];
  const float* proj_w = (const float*)d_in[4];
  const float* proj_b = (const float*)d_in[5];
  const float* rtab   = (const float*)d_in[6];
  const int*   ridx   = (const int*)d_in[7];
  float* out = (float*)d_out;

  char* p = (char*)d_ws;
  auto alloc = [&](size_t bytes) { char* r = p; p += (bytes + 255) & ~(size_t)255; return r; };
  ushort* xb    = (ushort*)alloc((size_t)BQ*NTOK*DIMC*2);    // 154.1 MB bf16 x
  ushort* QKVb  = (ushort*)alloc((size_t)BQ*NTOK*QKVN*2);    // 462.4 MB QKV rows
  ushort* Ob    = (ushort*)alloc((size_t)BQ*NTOK*DIMC*2);    // 154.1 MB
  ushort* qw    = (ushort*)alloc((size_t)QKVN*DIMC*2);
  ushort* pw    = (ushort*)alloc((size_t)DIMC*DIMC*2);
  float*  cbP   = (float*)alloc((size_t)NW*NH*16*64*4*4);    // 12.6 MB MFMA-layout bias+mask
  float*  qbias = (float*)alloc((size_t)QKVN*4);

  const int n8 = BQ*NTOK*DIMC/8;
  cast_x_kernel<<<2048, 256, 0, stream>>>(x, xb, n8);
  prep_kernel<<<(PREP_N1+PREP_N2+PREP_N3+PREP_N4 + 255)/256, 256, 0, stream>>>(
      qkv_w, proj_w, rtab, ridx, mask, qkv_b, qw, pw, cbP, qbias);

  // QKV: M=200704, N=1152, K=384 -> 1568*9 = 14112 blocks (div by 8)
  gemm_bt_kernel<1, DIMC, 9><<<14112, 256, 0, stream>>>(xb, qw, qbias, nullptr, QKVb);

  attn_kernel<<<BQ, 256, 0, stream>>>(QKVb, cbP, Ob);

  // proj: M=200704, N=384 -> 1568*3 = 4704 blocks (div by 8)
  gemm_bt_kernel<0, DIMC, 3><<<4704, 256, 0, stream>>>(Ob, pw, proj_b, out, nullptr);
}